// Round 8
// baseline (3299.239 us; speedup 1.0000x reference)
//
#include <hip/hip_runtime.h>

#define Tn 8
#define Nn 10000
#define FIN 128
#define Hh 64
#define En 160000
#define NODES (Tn * Nn)

typedef _Float16 h8 __attribute__((ext_vector_type(8)));
typedef _Float16 h4 __attribute__((ext_vector_type(4)));
typedef float f4v __attribute__((ext_vector_type(4)));

#define KT 2.8853900817779268f  // 2*log2(e)

__device__ __forceinline__ float sigm(float x) {
    float e = __builtin_amdgcn_exp2f(-1.4426950408889634f * x);
    return __builtin_amdgcn_rcpf(1.0f + e);
}
__device__ __forceinline__ float tanh_(float x) {
    float e = __builtin_amdgcn_exp2f(KT * x);
    return 1.0f - 2.0f * __builtin_amdgcn_rcpf(1.0f + e);
}

// edge_index may arrive as int32 or int64; detect by checking high words.
__global__ void k_detect(const unsigned* ei, int* flag) {
    unsigned a = 0;
    for (int i = threadIdx.x; i < 4096; i += 64) a |= ei[2 * i + 1];
    unsigned long long b = __ballot(a != 0);
    if (threadIdx.x == 0) flag[0] = (b != 0ull) ? 1 : 0;  // 1 => int32
}

__device__ __forceinline__ int eget(const void* ei, int is32, size_t pos) {
    return is32 ? ((const int*)ei)[pos] : (int)((const long long*)ei)[pos];
}

__global__ void k_cnt(const void* ei, const int* flag, int* cnt) {
    int tid = blockIdx.x * 256 + threadIdx.x;  // exactly Tn*En
    int is32 = *flag;
    int t = tid / En, e = tid - t * En;
    int dst = eget(ei, is32, (size_t)t * 2 * En + En + e);
    atomicAdd(&cnt[t * Nn + dst], 1);
}

// --- exclusive prefix sum over cnt[NODES]: A) block sums (+dinv), B) scan, C) combine
__global__ void k_scanA(const int* cnt, int* bsum, float* dinv) {
    __shared__ int sh[256];
    int i = blockIdx.x * 256 + threadIdx.x;
    int v = (i < NODES) ? cnt[i] : 0;
    if (i < NODES) dinv[i] = rsqrtf((float)v + 1.0f);  // +1 self-loop
    sh[threadIdx.x] = v;
    __syncthreads();
    for (int s = 128; s > 0; s >>= 1) {
        if (threadIdx.x < s) sh[threadIdx.x] += sh[threadIdx.x + s];
        __syncthreads();
    }
    if (threadIdx.x == 0) bsum[blockIdx.x] = sh[0];
}

__global__ void k_scanB(int* bsum, int nb) {
    __shared__ int sh[512];
    int v = (threadIdx.x < nb) ? bsum[threadIdx.x] : 0;
    sh[threadIdx.x] = v;
    __syncthreads();
    for (int s = 1; s < 512; s <<= 1) {
        int a = ((int)threadIdx.x >= s) ? sh[threadIdx.x - s] : 0;
        __syncthreads();
        sh[threadIdx.x] += a;
        __syncthreads();
    }
    if (threadIdx.x < nb) bsum[threadIdx.x] = sh[threadIdx.x] - v;  // exclusive
}

__global__ void k_scanC(const int* cnt, const int* bsum, int* off, int* cur) {
    __shared__ int sh[256];
    int i = blockIdx.x * 256 + threadIdx.x;
    int v = (i < NODES) ? cnt[i] : 0;
    sh[threadIdx.x] = v;
    __syncthreads();
    for (int s = 1; s < 256; s <<= 1) {
        int a = ((int)threadIdx.x >= s) ? sh[threadIdx.x - s] : 0;
        __syncthreads();
        sh[threadIdx.x] += a;
        __syncthreads();
    }
    int excl = sh[threadIdx.x] - v + bsum[blockIdx.x];
    if (i < NODES) { off[i] = excl; cur[i] = excl; }
}

__global__ void k_fill(const void* ei, const int* flag, int* cur, int* elist) {
    int tid = blockIdx.x * 256 + threadIdx.x;  // exactly Tn*En
    int is32 = *flag;
    int t = tid / En, e = tid - t * En;
    int src = eget(ei, is32, (size_t)t * 2 * En + e);
    int dst = eget(ei, is32, (size_t)t * 2 * En + En + e);
    int pos = atomicAdd(&cur[t * Nn + dst], 1);
    elist[pos] = t * Nn + src;
}

// hs = (x @ W_gcn) * dinv[row]   [Tn*Nn,128]@[128,64], dinv folded at write.
// Register-blocked: 16 rows/block, 4 outputs/thread -> 1 LDS vector-read per 4 FMA.
__global__ void k_gcn_mm(const float* __restrict__ x, const float* __restrict__ Wg,
                         const float* __restrict__ dinv, float* __restrict__ hs) {
    __shared__ float wl[FIN * Hh];   // 32 KB
    __shared__ float xs[16][FIN];    // 8 KB
    int tid = threadIdx.x;
    for (int i = tid; i < FIN * Hh / 4; i += 256)
        ((float4*)wl)[i] = ((const float4*)Wg)[i];
    int r0 = blockIdx.x * 16;
    const float4* x4 = (const float4*)(x + (size_t)r0 * FIN);
    ((float4*)xs)[tid] = x4[tid];
    ((float4*)xs)[tid + 256] = x4[tid + 256];
    __syncthreads();
    int c = tid & 63, jg = tid >> 6;  // wave jg handles rows jg*4..jg*4+3
    float acc[4] = {0.f, 0.f, 0.f, 0.f};
#pragma unroll 4
    for (int k = 0; k < FIN; k++) {
        float wv = wl[k * Hh + c];
#pragma unroll
        for (int r = 0; r < 4; r++) acc[r] += xs[jg * 4 + r][k] * wv;
    }
#pragma unroll
    for (int r = 0; r < 4; r++) {
        int row = r0 + jg * 4 + r;
        hs[(size_t)row * Hh + c] = acc[r] * dinv[row];
    }
}

// Fused gather + xw:
//   g[node] = relu( (sum_{src in CSR} hs[src] + hs[node]) * dinv[node] + b_gcn )
//   xw[node] = g[node] @ W_ih^T + b_ih + b_hh  -> f16 [node][cell 0..63][gate 0..3]
// 16 nodes/block: gather phase (16 lanes/node) -> LDS -> matmul phase (1 gate-row/thread).
__global__ void k_gxw(const int* __restrict__ off, const int* __restrict__ cnt,
                      const int* __restrict__ elist, const float* __restrict__ hs,
                      const float* __restrict__ dinv, const float* __restrict__ bg,
                      const float* __restrict__ Wih, const float* __restrict__ bih,
                      const float* __restrict__ bhh, _Float16* __restrict__ xw) {
    __shared__ float xs[16][Hh];  // 4 KB
    int tid = threadIdx.x;
    int jj = tid >> 4;            // node-local 0..15
    int l16 = tid & 15;
    int grp = blockIdx.x * 16 + jj;
    int start = off[grp], n = cnt[grp];
    float4 acc = {0.f, 0.f, 0.f, 0.f};
    for (int k = 0; k < n; k++) {
        int s = elist[start + k];
        float4 v = ((const float4*)(hs + (size_t)s * Hh))[l16];
        acc.x += v.x;
        acc.y += v.y;
        acc.z += v.z;
        acc.w += v.w;
    }
    float dd = dinv[grp];
    float4 hv = ((const float4*)(hs + (size_t)grp * Hh))[l16];
    float4 b = ((const float4*)bg)[l16];
    acc.x = fmaxf((acc.x + hv.x) * dd + b.x, 0.f);
    acc.y = fmaxf((acc.y + hv.y) * dd + b.y, 0.f);
    acc.z = fmaxf((acc.z + hv.z) * dd + b.z, 0.f);
    acc.w = fmaxf((acc.w + hv.w) * dd + b.w, 0.f);
    ((float4*)xs[jj])[l16] = acc;
    __syncthreads();

    int r = tid;  // gate-row 0..255; col r = q*64 + cell -> store [row][cell][q]
    const float4* w4 = (const float4*)(Wih + (size_t)r * Hh);
    float a2[16];
#pragma unroll
    for (int j = 0; j < 16; j++) a2[j] = 0.f;
#pragma unroll
    for (int kk = 0; kk < 16; kk++) {
        float4 w = w4[kk];
#pragma unroll
        for (int j = 0; j < 16; j++) {
            float4 xv = ((const float4*)xs[j])[kk];
            a2[j] += w.x * xv.x + w.y * xv.y + w.z * xv.z + w.w * xv.w;
        }
    }
    float bias = bih[r] + bhh[r];
    int cell = r & 63, q = r >> 6;
    int r0 = blockIdx.x * 16;
#pragma unroll
    for (int j = 0; j < 16; j++)
        xw[(size_t)(r0 + j) * 256 + cell * 4 + q] = (_Float16)(a2[j] + bias);
}

// One chain per 4-wave block. Wave w owns cells 16w..16w+15 across all 4 gate
// quadrants (8 MFMAs/wave/step, breadth-first: all a0-half then all a1-half).
// Every lane holds all 4 gates of its cell in acc{0..3}[0]; no cross-lane ops.
// State is prescaled: cs = K*c, so exp2(cs) needs no mul on the critical chain.
// The global out-store of step n is issued in step n+1's post-barrier ds_read
// shadow (lagged), flushed after the loop. lgkm-only barrier: global loads and
// stores never drained.
__global__ void __launch_bounds__(256, 1) k_lstm(const _Float16* __restrict__ xw,
                                                 const float* __restrict__ Whh,
                                                 float* __restrict__ out) {
    __shared__ __align__(16) _Float16 hb[2][64];
    int t = blockIdx.x;
    int tid = threadIdx.x;
    int w = tid >> 6;
    int lane = tid & 63;
    int l = lane & 15;
    int kg = lane >> 4;
    int col = w * 16 + l;  // cell index this lane's wave computes

    // B frags: quadrant q covers W_hh rows q*64+col; lane (kg,l) holds k=kg*8+j (+32*half)
    h8 bf[4][2];
#pragma unroll
    for (int q = 0; q < 4; q++) {
        int row = q * 64 + col;
#pragma unroll
        for (int half = 0; half < 2; half++) {
            const float* src = Whh + (size_t)row * 64 + half * 32 + kg * 8;
            h8 tmp;
#pragma unroll
            for (int j = 0; j < 8; j++) tmp[j] = (_Float16)src[j];
            bf[q][half] = tmp;
        }
    }
    if (tid < 128) hb[tid >> 6][tid & 63] = (_Float16)0.f;
    __syncthreads();  // init barrier only

    // xw stream: [row][cell][gate] f16; lane loads cell col's 4 gates as one 8B read
    const h4* xr = (const h4*)(xw + (size_t)t * Nn * 256) + col;  // stride 64 h4/row
    float* ob = out + (size_t)t * Nn * 64;

    h4 pf[4];
#pragma unroll
    for (int d = 0; d < 4; d++) pf[d] = xr[(size_t)d * 64];
    float cs = 0.f;    // prescaled cell state K*c
    float hvp = 0.f;   // lagged h value (stored next step)
    f4v acc0 = {0.f, 0.f, 0.f, 0.f};
    f4v acc1 = {0.f, 0.f, 0.f, 0.f};
    f4v acc2 = {0.f, 0.f, 0.f, 0.f};
    f4v acc3 = {0.f, 0.f, 0.f, 0.f};

    for (int n4 = 0; n4 < Nn; n4 += 4) {
#pragma unroll
        for (int u = 0; u < 4; u++) {
            int n = n4 + u;
            // ds_reads issue first (critical-path head)
            h8 a0 = *(const h8*)&hb[n & 1][kg * 8];
            h8 a1 = *(const h8*)&hb[n & 1][32 + kg * 8];
            // fill the ds_read latency shadow with independent work:
            // lagged global store of step n-1's h, xw prefetch, cvt + acc seeds
            if (lane < 16 && n > 0) ob[(size_t)(n - 1) * 64 + col] = hvp;
            h4 xc = pf[u];
            acc0[0] = (float)xc[0];
            acc1[0] = (float)xc[1];
            acc2[0] = (float)xc[2];
            acc3[0] = (float)xc[3];
            // prefetch 4 ahead; over-reads <=4 rows past xw into gout scratch (benign)
            pf[u] = xr[(size_t)(n + 4) * 64];

            // breadth-first MFMA issue: a0-half of all quadrants, then a1-half
            acc0 = __builtin_amdgcn_mfma_f32_16x16x32_f16(a0, bf[0][0], acc0, 0, 0, 0);
            acc1 = __builtin_amdgcn_mfma_f32_16x16x32_f16(a0, bf[1][0], acc1, 0, 0, 0);
            acc2 = __builtin_amdgcn_mfma_f32_16x16x32_f16(a0, bf[2][0], acc2, 0, 0, 0);
            acc3 = __builtin_amdgcn_mfma_f32_16x16x32_f16(a0, bf[3][0], acc3, 0, 0, 0);
            acc0 = __builtin_amdgcn_mfma_f32_16x16x32_f16(a1, bf[0][1], acc0, 0, 0, 0);
            acc1 = __builtin_amdgcn_mfma_f32_16x16x32_f16(a1, bf[1][1], acc1, 0, 0, 0);
            acc2 = __builtin_amdgcn_mfma_f32_16x16x32_f16(a1, bf[2][1], acc2, 0, 0, 0);
            acc3 = __builtin_amdgcn_mfma_f32_16x16x32_f16(a1, bf[3][1], acc3, 0, 0, 0);

            // gates (trans in completion order); cs-chain: gv -> mul -> fma -> exp2
            float iv = sigm(acc0[0]);
            float fv = sigm(acc1[0]);
            float gv = tanh_(acc2[0]);
            float ov = sigm(acc3[0]);
            float ik = KT * iv;           // off-path (iv ready before gv)
            cs = fv * cs + ik * gv;       // prescaled: exp2(cs) directly below
            float e2 = __builtin_amdgcn_exp2f(cs);
            float tc = 1.0f - 2.0f * __builtin_amdgcn_rcpf(1.0f + e2);
            float hv = ov * tc;
            hvp = hv;

            if (lane < 16) {  // kg==0 lanes write the wave's 16 cells
                hb[(n + 1) & 1][col] = (_Float16)hv;  // ds_write only (store lagged)
            }
            // barrier draining LDS only; global loads/stores stay in flight
            asm volatile("s_waitcnt lgkmcnt(0)\n\ts_barrier" ::: "memory");
        }
    }
    if (lane < 16) ob[(size_t)(Nn - 1) * 64 + col] = hvp;  // flush last step
}

extern "C" void kernel_launch(void* const* d_in, const int* in_sizes, int n_in,
                              void* d_out, int out_size, void* d_ws, size_t ws_size,
                              hipStream_t stream) {
    const float* x = (const float*)d_in[0];
    const void* ei = d_in[1];
    const float* Wg = (const float*)d_in[2];
    const float* bg = (const float*)d_in[3];
    const float* Wih = (const float*)d_in[4];
    const float* Whh = (const float*)d_in[5];
    const float* bih = (const float*)d_in[6];
    const float* bhh = (const float*)d_in[7];
    float* out = (float*)d_out;

    char* ws = (char*)d_ws;
    _Float16* xw = (_Float16*)(ws);            // 40,960,000
    float* gout = (float*)(ws + 40960000);     // 20,480,000 (dead scratch; absorbs xw over-read)
    float* hs = (float*)(ws + 61440000);       // 20,480,000  (h * dinv, f32)
    float* dinv = (float*)(ws + 81920000);     //    320,000
    int* cnt = (int*)(ws + 82240000);          //    320,000
    int* off = (int*)(ws + 82560000);          //    320,000
    int* cur = (int*)(ws + 82880000);          //    320,000
    int* elist = (int*)(ws + 83200000);        //  5,120,000
    int* bsum = (int*)(ws + 88320000);         //      2,048
    int* flag = (int*)(ws + 88322048);         //         16
    (void)gout;

    const int NB = (NODES + 255) / 256;  // 313

    hipMemsetAsync(cnt, 0, NODES * sizeof(int), stream);
    k_detect<<<1, 64, 0, stream>>>((const unsigned*)ei, flag);
    k_cnt<<<Tn * En / 256, 256, 0, stream>>>(ei, flag, cnt);
    k_scanA<<<NB, 256, 0, stream>>>(cnt, bsum, dinv);
    k_scanB<<<1, 512, 0, stream>>>(bsum, NB);
    k_scanC<<<NB, 256, 0, stream>>>(cnt, bsum, off, cur);
    k_fill<<<Tn * En / 256, 256, 0, stream>>>(ei, flag, cur, elist);
    k_gcn_mm<<<Tn * Nn / 16, 256, 0, stream>>>(x, Wg, dinv, hs);
    k_gxw<<<NODES / 16, 256, 0, stream>>>(off, cnt, elist, hs, dinv, bg, Wih, bih, bhh, xw);
    k_lstm<<<Tn, 256, 0, stream>>>(xw, Whh, out);
}

// Round 9
// 2966.204 us; speedup vs baseline: 1.1123x; 1.1123x over previous
//
#include <hip/hip_runtime.h>

#define Tn 8
#define Nn 10000
#define FIN 128
#define Hh 64
#define En 160000
#define NODES (Tn * Nn)

typedef _Float16 h8 __attribute__((ext_vector_type(8)));
typedef _Float16 h4 __attribute__((ext_vector_type(4)));
typedef float f4v __attribute__((ext_vector_type(4)));

__device__ __forceinline__ float sigm(float x) {
    float e = __builtin_amdgcn_exp2f(-1.4426950408889634f * x);
    return __builtin_amdgcn_rcpf(1.0f + e);
}
__device__ __forceinline__ float tanh_(float x) {
    float e = __builtin_amdgcn_exp2f(2.8853900817779268f * x);
    return 1.0f - 2.0f * __builtin_amdgcn_rcpf(1.0f + e);
}

// edge_index may arrive as int32 or int64; detect by checking high words.
__global__ void k_detect(const unsigned* ei, int* flag) {
    unsigned a = 0;
    for (int i = threadIdx.x; i < 4096; i += 64) a |= ei[2 * i + 1];
    unsigned long long b = __ballot(a != 0);
    if (threadIdx.x == 0) flag[0] = (b != 0ull) ? 1 : 0;  // 1 => int32
}

__device__ __forceinline__ int eget(const void* ei, int is32, size_t pos) {
    return is32 ? ((const int*)ei)[pos] : (int)((const long long*)ei)[pos];
}

__global__ void k_cnt(const void* ei, const int* flag, int* cnt) {
    int tid = blockIdx.x * 256 + threadIdx.x;  // exactly Tn*En
    int is32 = *flag;
    int t = tid / En, e = tid - t * En;
    int dst = eget(ei, is32, (size_t)t * 2 * En + En + e);
    atomicAdd(&cnt[t * Nn + dst], 1);
}

// --- exclusive prefix sum over cnt[NODES]: A) block sums (+dinv), B) scan, C) combine
__global__ void k_scanA(const int* cnt, int* bsum, float* dinv) {
    __shared__ int sh[256];
    int i = blockIdx.x * 256 + threadIdx.x;
    int v = (i < NODES) ? cnt[i] : 0;
    if (i < NODES) dinv[i] = rsqrtf((float)v + 1.0f);  // +1 self-loop
    sh[threadIdx.x] = v;
    __syncthreads();
    for (int s = 128; s > 0; s >>= 1) {
        if (threadIdx.x < s) sh[threadIdx.x] += sh[threadIdx.x + s];
        __syncthreads();
    }
    if (threadIdx.x == 0) bsum[blockIdx.x] = sh[0];
}

__global__ void k_scanB(int* bsum, int nb) {
    __shared__ int sh[512];
    int v = (threadIdx.x < nb) ? bsum[threadIdx.x] : 0;
    sh[threadIdx.x] = v;
    __syncthreads();
    for (int s = 1; s < 512; s <<= 1) {
        int a = ((int)threadIdx.x >= s) ? sh[threadIdx.x - s] : 0;
        __syncthreads();
        sh[threadIdx.x] += a;
        __syncthreads();
    }
    if (threadIdx.x < nb) bsum[threadIdx.x] = sh[threadIdx.x] - v;  // exclusive
}

__global__ void k_scanC(const int* cnt, const int* bsum, int* off, int* cur) {
    __shared__ int sh[256];
    int i = blockIdx.x * 256 + threadIdx.x;
    int v = (i < NODES) ? cnt[i] : 0;
    sh[threadIdx.x] = v;
    __syncthreads();
    for (int s = 1; s < 256; s <<= 1) {
        int a = ((int)threadIdx.x >= s) ? sh[threadIdx.x - s] : 0;
        __syncthreads();
        sh[threadIdx.x] += a;
        __syncthreads();
    }
    int excl = sh[threadIdx.x] - v + bsum[blockIdx.x];
    if (i < NODES) { off[i] = excl; cur[i] = excl; }
}

__global__ void k_fill(const void* ei, const int* flag, int* cur, int* elist) {
    int tid = blockIdx.x * 256 + threadIdx.x;  // exactly Tn*En
    int is32 = *flag;
    int t = tid / En, e = tid - t * En;
    int src = eget(ei, is32, (size_t)t * 2 * En + e);
    int dst = eget(ei, is32, (size_t)t * 2 * En + En + e);
    int pos = atomicAdd(&cur[t * Nn + dst], 1);
    elist[pos] = t * Nn + src;
}

// hs = (x @ W_gcn) * dinv[row]   [Tn*Nn,128]@[128,64], dinv folded at write.
// Register-blocked: 16 rows/block, 4 outputs/thread -> 1 LDS vector-read per 4 FMA.
__global__ void k_gcn_mm(const float* __restrict__ x, const float* __restrict__ Wg,
                         const float* __restrict__ dinv, float* __restrict__ hs) {
    __shared__ float wl[FIN * Hh];   // 32 KB
    __shared__ float xs[16][FIN];    // 8 KB
    int tid = threadIdx.x;
    for (int i = tid; i < FIN * Hh / 4; i += 256)
        ((float4*)wl)[i] = ((const float4*)Wg)[i];
    int r0 = blockIdx.x * 16;
    const float4* x4 = (const float4*)(x + (size_t)r0 * FIN);
    ((float4*)xs)[tid] = x4[tid];
    ((float4*)xs)[tid + 256] = x4[tid + 256];
    __syncthreads();
    int c = tid & 63, jg = tid >> 6;  // wave jg handles rows jg*4..jg*4+3
    float acc[4] = {0.f, 0.f, 0.f, 0.f};
#pragma unroll 4
    for (int k = 0; k < FIN; k++) {
        float wv = wl[k * Hh + c];
#pragma unroll
        for (int r = 0; r < 4; r++) acc[r] += xs[jg * 4 + r][k] * wv;
    }
#pragma unroll
    for (int r = 0; r < 4; r++) {
        int row = r0 + jg * 4 + r;
        hs[(size_t)row * Hh + c] = acc[r] * dinv[row];
    }
}

// Fused gather + xw:
//   g[node] = relu( (sum_{src in CSR} hs[src] + hs[node]) * dinv[node] + b_gcn )
//   xw[node] = g[node] @ W_ih^T + b_ih + b_hh  -> f16 [node][cell 0..63][gate 0..3]
// 16 nodes/block: gather phase (16 lanes/node) -> LDS -> matmul phase (1 gate-row/thread).
__global__ void k_gxw(const int* __restrict__ off, const int* __restrict__ cnt,
                      const int* __restrict__ elist, const float* __restrict__ hs,
                      const float* __restrict__ dinv, const float* __restrict__ bg,
                      const float* __restrict__ Wih, const float* __restrict__ bih,
                      const float* __restrict__ bhh, _Float16* __restrict__ xw) {
    __shared__ float xs[16][Hh];  // 4 KB
    int tid = threadIdx.x;
    int jj = tid >> 4;            // node-local 0..15
    int l16 = tid & 15;
    int grp = blockIdx.x * 16 + jj;
    int start = off[grp], n = cnt[grp];
    float4 acc = {0.f, 0.f, 0.f, 0.f};
    for (int k = 0; k < n; k++) {
        int s = elist[start + k];
        float4 v = ((const float4*)(hs + (size_t)s * Hh))[l16];
        acc.x += v.x;
        acc.y += v.y;
        acc.z += v.z;
        acc.w += v.w;
    }
    float dd = dinv[grp];
    float4 hv = ((const float4*)(hs + (size_t)grp * Hh))[l16];
    float4 b = ((const float4*)bg)[l16];
    acc.x = fmaxf((acc.x + hv.x) * dd + b.x, 0.f);
    acc.y = fmaxf((acc.y + hv.y) * dd + b.y, 0.f);
    acc.z = fmaxf((acc.z + hv.z) * dd + b.z, 0.f);
    acc.w = fmaxf((acc.w + hv.w) * dd + b.w, 0.f);
    ((float4*)xs[jj])[l16] = acc;
    __syncthreads();

    int r = tid;  // gate-row 0..255; col r = q*64 + cell -> store [row][cell][q]
    const float4* w4 = (const float4*)(Wih + (size_t)r * Hh);
    float a2[16];
#pragma unroll
    for (int j = 0; j < 16; j++) a2[j] = 0.f;
#pragma unroll
    for (int kk = 0; kk < 16; kk++) {
        float4 w = w4[kk];
#pragma unroll
        for (int j = 0; j < 16; j++) {
            float4 xv = ((const float4*)xs[j])[kk];
            a2[j] += w.x * xv.x + w.y * xv.y + w.z * xv.z + w.w * xv.w;
        }
    }
    float bias = bih[r] + bhh[r];
    int cell = r & 63, q = r >> 6;
    int r0 = blockIdx.x * 16;
#pragma unroll
    for (int j = 0; j < 16; j++)
        xw[(size_t)(r0 + j) * 256 + cell * 4 + q] = (_Float16)(a2[j] + bias);
}

// One chain per 4-wave block (exact R7-bench structure = 620cy/step best).
// Wave w owns cells 16w..16w+15 across all 4 gate quadrants (8 MFMAs/wave/step,
// breadth-first: all a0-half then all a1-half — in-order issue means adjacent
// dependent pairs stall; breadth-first removes that). Every lane holds all 4 gates
// of its cell in acc{0..3}[0]; no cross-lane ops. Trans block AFTER all MFMAs.
// acc tuples persist across steps ([1..3] accumulate bounded garbage, rows are
// independent, f32-safe); only [0] re-seeded. Stores pre-barrier; lgkm-only
// barrier keeps global loads/stores in flight.
__global__ void __launch_bounds__(256, 1) k_lstm(const _Float16* __restrict__ xw,
                                                 const float* __restrict__ Whh,
                                                 float* __restrict__ out) {
    __shared__ __align__(16) _Float16 hb[2][64];
    int t = blockIdx.x;
    int tid = threadIdx.x;
    int w = tid >> 6;
    int lane = tid & 63;
    int l = lane & 15;
    int kg = lane >> 4;
    int col = w * 16 + l;  // cell index this lane's wave computes

    // B frags: quadrant q covers W_hh rows q*64+col; lane (kg,l) holds k=kg*8+j (+32*half)
    h8 bf[4][2];
#pragma unroll
    for (int q = 0; q < 4; q++) {
        int row = q * 64 + col;
#pragma unroll
        for (int half = 0; half < 2; half++) {
            const float* src = Whh + (size_t)row * 64 + half * 32 + kg * 8;
            h8 tmp;
#pragma unroll
            for (int j = 0; j < 8; j++) tmp[j] = (_Float16)src[j];
            bf[q][half] = tmp;
        }
    }
    if (tid < 128) hb[tid >> 6][tid & 63] = (_Float16)0.f;
    __syncthreads();  // init barrier only

    // xw stream: [row][cell][gate] f16; lane loads cell col's 4 gates as one 8B read
    const h4* xr = (const h4*)(xw + (size_t)t * Nn * 256) + col;  // stride 64 h4/row
    float* ob = out + (size_t)t * Nn * 64;

    h4 pf[4];
#pragma unroll
    for (int d = 0; d < 4; d++) pf[d] = xr[(size_t)d * 64];
    float c = 0.f;
    f4v acc0 = {0.f, 0.f, 0.f, 0.f};
    f4v acc1 = {0.f, 0.f, 0.f, 0.f};
    f4v acc2 = {0.f, 0.f, 0.f, 0.f};
    f4v acc3 = {0.f, 0.f, 0.f, 0.f};

    for (int n4 = 0; n4 < Nn; n4 += 4) {
#pragma unroll
        for (int u = 0; u < 4; u++) {
            int n = n4 + u;
            // ds_reads issue first (critical-path head)
            h8 a0 = *(const h8*)&hb[n & 1][kg * 8];
            h8 a1 = *(const h8*)&hb[n & 1][32 + kg * 8];
            // cvt + acc[0] seeds overlap the ds_read latency (no lgkm dep)
            h4 xc = pf[u];
            acc0[0] = (float)xc[0];
            acc1[0] = (float)xc[1];
            acc2[0] = (float)xc[2];
            acc3[0] = (float)xc[3];
            // prefetch 4 ahead; over-reads <=4 rows past xw into scratch (benign)
            pf[u] = xr[(size_t)(n + 4) * 64];

            // breadth-first MFMA issue: a0-half of all quadrants, then a1-half
            acc0 = __builtin_amdgcn_mfma_f32_16x16x32_f16(a0, bf[0][0], acc0, 0, 0, 0);
            acc1 = __builtin_amdgcn_mfma_f32_16x16x32_f16(a0, bf[1][0], acc1, 0, 0, 0);
            acc2 = __builtin_amdgcn_mfma_f32_16x16x32_f16(a0, bf[2][0], acc2, 0, 0, 0);
            acc3 = __builtin_amdgcn_mfma_f32_16x16x32_f16(a0, bf[3][0], acc3, 0, 0, 0);
            acc0 = __builtin_amdgcn_mfma_f32_16x16x32_f16(a1, bf[0][1], acc0, 0, 0, 0);
            acc1 = __builtin_amdgcn_mfma_f32_16x16x32_f16(a1, bf[1][1], acc1, 0, 0, 0);
            acc2 = __builtin_amdgcn_mfma_f32_16x16x32_f16(a1, bf[2][1], acc2, 0, 0, 0);
            acc3 = __builtin_amdgcn_mfma_f32_16x16x32_f16(a1, bf[3][1], acc3, 0, 0, 0);

            // trans in acc completion order
            float iv = sigm(acc0[0]);
            float fv = sigm(acc1[0]);
            float gv = tanh_(acc2[0]);
            float ov = sigm(acc3[0]);
            c = fv * c + iv * gv;
            float tc = tanh_(c);
            float hv = ov * tc;

            if (lane < 16) {  // kg==0 lanes write the wave's 16 cells
                hb[(n + 1) & 1][col] = (_Float16)hv;  // ds_write first
                ob[(size_t)n * 64 + col] = hv;        // global store (no lgkm effect)
            }
            // barrier draining LDS only; global loads/stores stay in flight
            asm volatile("s_waitcnt lgkmcnt(0)\n\ts_barrier" ::: "memory");
        }
    }
}

extern "C" void kernel_launch(void* const* d_in, const int* in_sizes, int n_in,
                              void* d_out, int out_size, void* d_ws, size_t ws_size,
                              hipStream_t stream) {
    const float* x = (const float*)d_in[0];
    const void* ei = d_in[1];
    const float* Wg = (const float*)d_in[2];
    const float* bg = (const float*)d_in[3];
    const float* Wih = (const float*)d_in[4];
    const float* Whh = (const float*)d_in[5];
    const float* bih = (const float*)d_in[6];
    const float* bhh = (const float*)d_in[7];
    float* out = (float*)d_out;

    char* ws = (char*)d_ws;
    _Float16* xw = (_Float16*)(ws);            // 40,960,000
    float* gout = (float*)(ws + 40960000);     // 20,480,000 (dead scratch; absorbs xw over-read)
    float* hs = (float*)(ws + 61440000);       // 20,480,000  (h * dinv, f32)
    float* dinv = (float*)(ws + 81920000);     //    320,000
    int* cnt = (int*)(ws + 82240000);          //    320,000
    int* off = (int*)(ws + 82560000);          //    320,000
    int* cur = (int*)(ws + 82880000);          //    320,000
    int* elist = (int*)(ws + 83200000);        //  5,120,000
    int* bsum = (int*)(ws + 88320000);         //      2,048
    int* flag = (int*)(ws + 88322048);         //         16
    (void)gout;

    const int NB = (NODES + 255) / 256;  // 313

    hipMemsetAsync(cnt, 0, NODES * sizeof(int), stream);
    k_detect<<<1, 64, 0, stream>>>((const unsigned*)ei, flag);
    k_cnt<<<Tn * En / 256, 256, 0, stream>>>(ei, flag, cnt);
    k_scanA<<<NB, 256, 0, stream>>>(cnt, bsum, dinv);
    k_scanB<<<1, 512, 0, stream>>>(bsum, NB);
    k_scanC<<<NB, 256, 0, stream>>>(cnt, bsum, off, cur);
    k_fill<<<Tn * En / 256, 256, 0, stream>>>(ei, flag, cur, elist);
    k_gcn_mm<<<Tn * Nn / 16, 256, 0, stream>>>(x, Wg, dinv, hs);
    k_gxw<<<NODES / 16, 256, 0, stream>>>(off, cnt, elist, hs, dinv, bg, Wih, bih, bhh, xw);
    k_lstm<<<Tn, 256, 0, stream>>>(xw, Whh, out);
}